// Round 5
// baseline (1200.366 us; speedup 1.0000x reference)
//
#include <hip/hip_runtime.h>
#include <math.h>

#define BB 16
#define TT 512
#define IND 128
#define HH 256
#define DD 8
#define EPSF 1e-5f

typedef _Float16 h8_t __attribute__((ext_vector_type(8)));
typedef float f32x4 __attribute__((ext_vector_type(4)));

__device__ __forceinline__ float fast_tanh(float x) {
    // exp->inf gives 1, exp->0 gives -1; no clamp needed (verified r1/r2/r4)
    const float e = __expf(2.f * x);
    return 1.f - __fdividef(2.f, e + 1.f);
}

// ---------------- K1: x_proj[b,t,j] = y[b,t,:]·W_ih[j,:] + b_ih[j] + b_hh[j] ----------------
__global__ __launch_bounds__(512, 4) void xproj_kernel(
    const float* __restrict__ y, const float* __restrict__ W_ih,
    const float* __restrict__ b_ih, const float* __restrict__ b_hh,
    float* __restrict__ xp)
{
    __shared__ __align__(16) float ylds[IND];
    const int tid = threadIdx.x;
    const int j = tid >> 1;
    const int k4 = (tid & 1) * 4;

    float4 w[16];
    const float* wr = W_ih + (size_t)j * IND + k4;
#pragma unroll
    for (int i = 0; i < 16; ++i) w[i] = *(const float4*)(wr + i * 8);
#pragma unroll
    for (int i = 0; i < 16; ++i)
        asm volatile("" : "+v"(w[i].x), "+v"(w[i].y), "+v"(w[i].z), "+v"(w[i].w));
    const float bias = b_ih[j] + b_hh[j];

    const int row0 = blockIdx.x * 16;
    for (int r = 0; r < 16; ++r) {
        const int row = row0 + r;
        if (tid < IND / 4) ((float4*)ylds)[tid] = ((const float4*)(y + (size_t)row * IND))[tid];
        __syncthreads();
        float a0 = 0.f, a1 = 0.f, a2 = 0.f, a3 = 0.f;
#pragma unroll
        for (int i = 0; i < 16; ++i) {
            const float4 hv = *(const float4*)(ylds + i * 8 + k4);
            a0 = fmaf(hv.x, w[i].x, a0);
            a1 = fmaf(hv.y, w[i].y, a1);
            a2 = fmaf(hv.z, w[i].z, a2);
            a3 = fmaf(hv.w, w[i].w, a3);
        }
        float acc = (a0 + a1) + (a2 + a3);
        acc += __shfl_xor(acc, 1);
        if ((tid & 1) == 0) xp[(size_t)row * HH + j] = acc + bias;
        __syncthreads();
    }
}

// ---------------- K2: per-batch MFMA RNN scan (blocks 0..15) + prec fill (blocks 16..) ----
// One block per batch on its own CU. 512 threads = 8 waves (2/SIMD). Wave w owns m-tiles
// {2w, 2w+1} (j in [32w, 32w+32)): af = 2x8 h8 = 64 VGPR pinned. B = h with ALL 16 MFMA
// columns fed identical data (16 lanes of an lr-group read the same 16 B -> broadcast,
// conflict-free): every column computes the same valid result, so every lane's C is valid
// with zero repacking/selects; 8 tanh/lane. h exchange: lanes lr==0 (4/wave) pack f16 and
// ds_write_b64 at stride-8 offsets (conflict-free). xp: 4-deep rotating register prefetch;
// lgkm-only barrier keeps global loads in flight across steps.
__global__ __launch_bounds__(512, 2) void scan_fill_kernel(
    const float* __restrict__ xp, const float* __restrict__ W_hh,
    float* __restrict__ enc, float* __restrict__ prec)
{
    if (blockIdx.x >= BB) {
        const size_t n4 = (size_t)BB * DD * TT * TT / 4;
        const f32x4 z = {0.f, 0.f, 0.f, 0.f};
        f32x4* p4 = (f32x4*)prec;
        size_t idx = (size_t)(blockIdx.x - BB) * blockDim.x + threadIdx.x;
        const size_t stride = (size_t)(gridDim.x - BB) * blockDim.x;
        for (; idx < n4; idx += stride) p4[idx] = z;
        return;
    }

    const int b   = blockIdx.x;
    const int tid = threadIdx.x;
    const int w   = tid >> 6;    // wave 0..7: m-tiles 2w, 2w+1
    const int l   = tid & 63;
    const int lr  = l & 15;      // A row-in-tile / C column (all columns identical)
    const int lh  = l >> 4;      // k-group 0..3
    const int mt0 = 2 * w, mt1 = 2 * w + 1;
    const int j0  = 16 * mt0 + 4 * lh;  // first owned j, tile 0 (rows 4lh..4lh+3)
    const int j1  = 16 * mt1 + 4 * lh;

    __shared__ __align__(16) _Float16 hA[HH], hB[HH];  // 512 B each, double-buffered

    // ---- A fragments: af{0,1}[kt] = W_hh[16mt+lr][32kt+8lh+e], pinned (64 VGPR) ----
    h8_t af0[8], af1[8];
#pragma unroll
    for (int kt = 0; kt < 8; ++kt) {
        const float* p0 = W_hh + (size_t)(16 * mt0 + lr) * HH + 32 * kt + 8 * lh;
        const float* p1 = W_hh + (size_t)(16 * mt1 + lr) * HH + 32 * kt + 8 * lh;
        const f32x4 a = *(const f32x4*)(p0);
        const f32x4 bq = *(const f32x4*)(p0 + 4);
        const f32x4 c = *(const f32x4*)(p1);
        const f32x4 d = *(const f32x4*)(p1 + 4);
        h8_t v0, v1;
#pragma unroll
        for (int e = 0; e < 4; ++e) {
            v0[e] = (_Float16)a[e]; v0[e + 4] = (_Float16)bq[e];
            v1[e] = (_Float16)c[e]; v1[e + 4] = (_Float16)d[e];
        }
        af0[kt] = v0; af1[kt] = v1;
    }
#pragma unroll
    for (int kt = 0; kt < 8; ++kt) {
        int4 t0 = __builtin_bit_cast(int4, af0[kt]);
        int4 t1 = __builtin_bit_cast(int4, af1[kt]);
        asm volatile("" : "+v"(t0.x), "+v"(t0.y), "+v"(t0.z), "+v"(t0.w));
        asm volatile("" : "+v"(t1.x), "+v"(t1.y), "+v"(t1.z), "+v"(t1.w));
        af0[kt] = __builtin_bit_cast(h8_t, t0);
        af1[kt] = __builtin_bit_cast(h8_t, t1);
    }

    // zero-init hA (h0 = 0)
    if (tid < 64) ((long*)hA)[tid] = 0L;

    const float* xpb  = xp  + (size_t)b * TT * HH;
    float*       encb = enc + (size_t)b * TT * HH;

    // 4-deep rotating xp prefetch (statically indexed via full unroll)
    f32x4 xq0[4], xq1[4];
#pragma unroll
    for (int s = 0; s < 4; ++s) {
        const int t = (s < TT) ? s : TT - 1;
        xq0[s] = *(const f32x4*)(xpb + (size_t)t * HH + j0);
        xq1[s] = *(const f32x4*)(xpb + (size_t)t * HH + j1);
    }

    __syncthreads();

    const char* hrd = (const char*)hA;
    char*       hwr = (char*)hB;

#define SCAN_STEP(TSTEP, X0, X1)                                                          \
    {                                                                                     \
        const int t_  = (TSTEP);                                                          \
        const int tp_ = (t_ + 4 < TT) ? t_ + 4 : TT - 1;                                  \
        const f32x4 c0 = X0, c1 = X1;                                                     \
        X0 = *(const f32x4*)(xpb + (size_t)tp_ * HH + j0);                                \
        X1 = *(const f32x4*)(xpb + (size_t)tp_ * HH + j1);                                \
        h8_t bf[8];                                                                       \
        _Pragma("unroll")                                                                 \
        for (int kt = 0; kt < 8; ++kt)                                                    \
            bf[kt] = *(const h8_t*)(hrd + kt * 64 + lh * 16);                             \
        f32x4 a0 = c0, a1 = c1;                                                           \
        _Pragma("unroll")                                                                 \
        for (int kt = 0; kt < 8; ++kt) {                                                  \
            a0 = __builtin_amdgcn_mfma_f32_16x16x32_f16(af0[kt], bf[kt], a0, 0, 0, 0);    \
            a1 = __builtin_amdgcn_mfma_f32_16x16x32_f16(af1[kt], bf[kt], a1, 0, 0, 0);    \
        }                                                                                 \
        f32x4 s0, s1;                                                                     \
        _Pragma("unroll")                                                                 \
        for (int r = 0; r < 4; ++r) { s0[r] = fast_tanh(a0[r]); s1[r] = fast_tanh(a1[r]); } \
        if (lr == 0) {                                                                    \
            *(f32x4*)(encb + (size_t)t_ * HH + j0) = s0;                                  \
            *(f32x4*)(encb + (size_t)t_ * HH + j1) = s1;                                  \
            int2 w0, w1;                                                                  \
            w0.x = __builtin_bit_cast(int, __builtin_amdgcn_cvt_pkrtz(s0[0], s0[1]));     \
            w0.y = __builtin_bit_cast(int, __builtin_amdgcn_cvt_pkrtz(s0[2], s0[3]));     \
            w1.x = __builtin_bit_cast(int, __builtin_amdgcn_cvt_pkrtz(s1[0], s1[1]));     \
            w1.y = __builtin_bit_cast(int, __builtin_amdgcn_cvt_pkrtz(s1[2], s1[3]));     \
            *(int2*)(hwr + (size_t)j0 * 2) = w0;                                          \
            *(int2*)(hwr + (size_t)j1 * 2) = w1;                                          \
        }                                                                                 \
        asm volatile("s_waitcnt lgkmcnt(0)\n\ts_barrier" ::: "memory");                   \
        { const char* tmp_ = hrd; hrd = hwr; hwr = (char*)tmp_; }                         \
    }

    for (int tb = 0; tb < TT; tb += 4) {
        SCAN_STEP(tb,     xq0[0], xq1[0])
        SCAN_STEP(tb + 1, xq0[1], xq1[1])
        SCAN_STEP(tb + 2, xq0[2], xq1[2])
        SCAN_STEP(tb + 3, xq0[3], xq1[3])
    }
#undef SCAN_STEP
}

// ---------------- K3: heads + tridiagonal fill ----------------
__global__ __launch_bounds__(256) void head_kernel(
    const float* __restrict__ enc,
    const float* __restrict__ W_mean, const float* __restrict__ b_mean,
    const float* __restrict__ W_bd, const float* __restrict__ b_bd,
    float* __restrict__ mean_out, float* __restrict__ prec)
{
    const int b = blockIdx.x >> 6;
    const int t0 = (blockIdx.x & 63) * 8;
    __shared__ __align__(16) float erow[9][HH];  // rows t0-1 .. t0+7
    __shared__ float vals[8][32];

    const int tid = threadIdx.x;
    {
        // row t0-1 (for t0==0,b==0 this reads the tail of xp — harmless, discarded)
        const float4* src = (const float4*)(enc + ((size_t)b * TT + t0) * HH - HH);
        float4* dst = (float4*)erow;
        for (int i = tid; i < 9 * (HH / 4); i += 256) dst[i] = src[i];
    }

    const int g = tid >> 3, m = tid & 7;
    const float* wrow;
    float bias;
    if (g < 8)       { wrow = W_mean + (size_t)g * HH;      bias = b_mean[g]; }
    else if (g < 24) { wrow = W_bd + (size_t)(g - 8) * HH;  bias = b_bd[g - 8]; }
    else             { wrow = W_bd + (size_t)(g - 16) * HH; bias = b_bd[g - 16]; }

    float4 wv[8];
#pragma unroll
    for (int i = 0; i < 8; ++i) wv[i] = ((const float4*)wrow)[m * 8 + i];

    __syncthreads();

    for (int r = 0; r < 8; ++r) {
        const float* src = (g >= 24) ? erow[r] : erow[r + 1];
        float acc = 0.f;
#pragma unroll
        for (int i = 0; i < 8; ++i) {
            const float4 hv = ((const float4*)src)[m * 8 + i];
            acc += wv[i].x * hv.x + wv[i].y * hv.y + wv[i].z * hv.z + wv[i].w * hv.w;
        }
        acc += __shfl_xor(acc, 1);
        acc += __shfl_xor(acc, 2);
        acc += __shfl_xor(acc, 4);
        if (m == 0) vals[r][g] = acc + bias;
    }
    __syncthreads();

    // write phase: 256 threads = 8 r-slots x 32 lanes
    const int r = tid >> 5, s = tid & 31;
    const int t = t0 + r;
    if (s < DD) {
        mean_out[((size_t)b * TT + t) * DD + s] = vals[r][s];
    } else if (s < 2 * DD) {
        const int d = s - DD;
        const float diag = vals[r][8 + d];
        const float off  = vals[r][16 + d];
        const float offp = (t > 0) ? vals[r][24 + d] : 0.f;
        const size_t rowbase = (((size_t)b * DD + d) * TT + t) * TT;
        prec[rowbase + t] = diag * diag + offp * offp + EPSF;
        if (t < TT - 1) {
            const float sv = diag * off;
            prec[rowbase + t + 1] = sv;                                 // (t, t+1)
            prec[(((size_t)b * DD + d) * TT + (t + 1)) * TT + t] = sv;  // (t+1, t)
        }
    }
}

extern "C" void kernel_launch(void* const* d_in, const int* in_sizes, int n_in,
                              void* d_out, int out_size, void* d_ws, size_t ws_size,
                              hipStream_t stream) {
    const float* y      = (const float*)d_in[0];
    const float* W_ih   = (const float*)d_in[1];
    const float* W_hh   = (const float*)d_in[2];
    const float* b_ih   = (const float*)d_in[3];
    const float* b_hh   = (const float*)d_in[4];
    const float* W_mean = (const float*)d_in[5];
    const float* b_mean = (const float*)d_in[6];
    const float* W_bd   = (const float*)d_in[7];
    const float* b_bd   = (const float*)d_in[8];

    float* out  = (float*)d_out;
    float* mean = out;                              // B*T*D floats
    float* prec = out + (size_t)BB * TT * DD;       // B*D*T*T floats

    float* xp  = (float*)d_ws;                      // B*T*H floats = 8 MB
    float* enc = xp + (size_t)BB * TT * HH;         // B*T*H floats = 8 MB

    xproj_kernel<<<512, 512, 0, stream>>>(y, W_ih, b_ih, b_hh, xp);
    scan_fill_kernel<<<1008, 512, 0, stream>>>(xp, W_hh, enc, prec);
    head_kernel<<<1024, 256, 0, stream>>>(enc, W_mean, b_mean, W_bd, b_bd, mean, prec);
}

// Round 6
// 459.499 us; speedup vs baseline: 2.6123x; 2.6123x over previous
//
#include <hip/hip_runtime.h>
#include <math.h>

#define BB 16
#define TT 512
#define IND 128
#define HH 256
#define DD 8
#define EPSF 1e-5f

typedef _Float16 h2_t __attribute__((ext_vector_type(2)));
typedef float f32x4 __attribute__((ext_vector_type(4)));

__device__ __forceinline__ float fast_tanh(float x) {
    x = fminf(fmaxf(x, -15.f), 15.f);
    const float e = __expf(2.f * x);
    return __fdividef(e - 1.f, e + 1.f);
}

// quad_perm XOR swaps on the VALU pipe (no LDS traffic)
__device__ __forceinline__ float dpp_xor1(float x) {
    int i = __builtin_bit_cast(int, x);
    i = __builtin_amdgcn_update_dpp(i, i, 0xB1, 0xF, 0xF, true);  // {1,0,3,2}
    return __builtin_bit_cast(float, i);
}
__device__ __forceinline__ float dpp_xor2(float x) {
    int i = __builtin_bit_cast(int, x);
    i = __builtin_amdgcn_update_dpp(i, i, 0x4E, 0xF, 0xF, true);  // {2,3,0,1}
    return __builtin_bit_cast(float, i);
}

// ---------------- K1: x_proj[b,t,j] = y[b,t,:]·W_ih[j,:] + b_ih[j] + b_hh[j] ----------------
__global__ __launch_bounds__(512, 4) void xproj_kernel(
    const float* __restrict__ y, const float* __restrict__ W_ih,
    const float* __restrict__ b_ih, const float* __restrict__ b_hh,
    float* __restrict__ xp)
{
    __shared__ __align__(16) float ylds[IND];
    const int tid = threadIdx.x;
    const int j = tid >> 1;
    const int k4 = (tid & 1) * 4;

    float4 w[16];
    const float* wr = W_ih + (size_t)j * IND + k4;
#pragma unroll
    for (int i = 0; i < 16; ++i) w[i] = *(const float4*)(wr + i * 8);
#pragma unroll
    for (int i = 0; i < 16; ++i)
        asm volatile("" : "+v"(w[i].x), "+v"(w[i].y), "+v"(w[i].z), "+v"(w[i].w));
    const float bias = b_ih[j] + b_hh[j];

    const int row0 = blockIdx.x * 16;
    for (int r = 0; r < 16; ++r) {
        const int row = row0 + r;
        if (tid < IND / 4) ((float4*)ylds)[tid] = ((const float4*)(y + (size_t)row * IND))[tid];
        __syncthreads();
        float a0 = 0.f, a1 = 0.f, a2 = 0.f, a3 = 0.f;
#pragma unroll
        for (int i = 0; i < 16; ++i) {
            const float4 hv = *(const float4*)(ylds + i * 8 + k4);
            a0 = fmaf(hv.x, w[i].x, a0);
            a1 = fmaf(hv.y, w[i].y, a1);
            a2 = fmaf(hv.z, w[i].z, a2);
            a3 = fmaf(hv.w, w[i].w, a3);
        }
        float acc = (a0 + a1) + (a2 + a3);
        acc += __shfl_xor(acc, 1);
        if ((tid & 1) == 0) xp[(size_t)row * HH + j] = acc + bias;
        __syncthreads();
    }
}

// ---------------- K2: RNN scan (blocks 0..15) + prec zero-fill (blocks 16..) ----------------
// r1's proven fdot2 scan widened to 512 threads = 8 waves (2/SIMD for latency overlap).
// Lane = (g = tid>>3, k = tid&7): owns cols {g+64m} with a 32-elem k-slice
// (elems [32k,32k+32)) -> 64 dot2/lane, 64 weight VGPRs, 4 ds_read_b128/lane.
// Per-instr LDS addresses: slice bytes (k>>1)*144 + (k&1)*64 + 16i -> 8 distinct starts
// covering all 32 banks, 8-way broadcast: conflict-free. Reduce over the 8 k-lanes:
// xor1/xor2 on DPP (VALU) + one shfl_xor(4); lane kk=k&3 keeps col g+64kk (k>=4 lanes
// duplicate, masked on write). 4-deep rotating xp prefetch; lgkm-only barrier keeps
// global loads in flight across steps.
__global__ __launch_bounds__(512, 2) void scan_fill_kernel(
    const float* __restrict__ xp, const float* __restrict__ W_hh,
    float* __restrict__ enc, float* __restrict__ prec)
{
    if (blockIdx.x >= BB) {
        const size_t n4 = (size_t)BB * DD * TT * TT / 4;
        const f32x4 z = {0.f, 0.f, 0.f, 0.f};
        f32x4* p4 = (f32x4*)prec;
        size_t idx = (size_t)(blockIdx.x - BB) * blockDim.x + threadIdx.x;
        const size_t stride = (size_t)(gridDim.x - BB) * blockDim.x;
        for (; idx < n4; idx += stride) p4[idx] = z;
        return;
    }

    const int b   = blockIdx.x;
    const int tid = threadIdx.x;
    const int g   = tid >> 3;      // 0..63 col group
    const int k   = tid & 7;       // 32-elem slice
    const int kk  = k & 3;         // owned-col selector
    const int jw  = g + 64 * kk;   // col this lane finalizes (k>=4 duplicates)
    const bool act = (k < 4);

    // h layout (r1-proven): 4 slices of 64 cols, slice s at byte s*144, col j at
    // (j>>6)*144 + (j&63)*2
    __shared__ __align__(16) char hbufA[4 * 144];
    __shared__ __align__(16) char hbufB[4 * 144];

    // weights: w[m][i] = (W_hh[g+64m][32k+2i], W_hh[g+64m][32k+2i+1]), i<16 (64 VGPR)
    h2_t w[4][16];
#pragma unroll
    for (int m = 0; m < 4; ++m) {
        const float* wr = W_hh + (size_t)(g + 64 * m) * HH + (size_t)k * 32;
#pragma unroll
        for (int i = 0; i < 16; ++i) {
            h2_t v;
            v.x = (_Float16)wr[2 * i];
            v.y = (_Float16)wr[2 * i + 1];
            w[m][i] = v;
        }
    }
#pragma unroll
    for (int m = 0; m < 4; ++m)
#pragma unroll
        for (int i = 0; i < 16; ++i) {
            int tmp = __builtin_bit_cast(int, w[m][i]);
            asm volatile("" : "+v"(tmp));
            w[m][i] = __builtin_bit_cast(h2_t, tmp);
        }

    // zero-init hbufA (pads don't matter: never read)
    if (tid < 128) {
        const int m = 2 * tid;
        h2_t z; z.x = (_Float16)0.f; z.y = (_Float16)0.f;
        *(h2_t*)(hbufA + (m >> 6) * 144 + (m & 63) * 2) = z;
    }

    const float* xpb  = xp  + (size_t)b * TT * HH;
    float*       encb = enc + (size_t)b * TT * HH;

    // 4-deep rotating xp prefetch (statically indexed via full unroll)
    float xbuf[4];
#pragma unroll
    for (int s = 0; s < 4; ++s) xbuf[s] = xpb[(size_t)s * HH + jw];

    __syncthreads();

    const char* hrd = hbufA;
    char* hwr = hbufB;

#define SCAN_STEP(TSTEP, S)                                                       \
    {                                                                             \
        const int t_ = (TSTEP);                                                   \
        const float xc = xbuf[S];                                                 \
        const int tp_ = (t_ + 4 < TT) ? t_ + 4 : TT - 1;                          \
        xbuf[S] = xpb[(size_t)tp_ * HH + jw];                                     \
        float a0 = 0.f, a1 = 0.f, a2 = 0.f, a3 = 0.f;                             \
        const float4* hp = (const float4*)(hrd + (k >> 1) * 144 + (k & 1) * 64);  \
        _Pragma("unroll")                                                         \
        for (int i = 0; i < 4; ++i) {                                             \
            union { float4 f4; h2_t h[4]; } u;                                    \
            u.f4 = hp[i];                                                         \
            _Pragma("unroll")                                                     \
            for (int e = 0; e < 4; ++e) {                                         \
                a0 = __builtin_amdgcn_fdot2(u.h[e], w[0][4 * i + e], a0, false);  \
                a1 = __builtin_amdgcn_fdot2(u.h[e], w[1][4 * i + e], a1, false);  \
                a2 = __builtin_amdgcn_fdot2(u.h[e], w[2][4 * i + e], a2, false);  \
                a3 = __builtin_amdgcn_fdot2(u.h[e], w[3][4 * i + e], a3, false);  \
            }                                                                     \
        }                                                                         \
        a0 += dpp_xor1(a0); a0 += dpp_xor2(a0); a0 += __shfl_xor(a0, 4);          \
        a1 += dpp_xor1(a1); a1 += dpp_xor2(a1); a1 += __shfl_xor(a1, 4);          \
        a2 += dpp_xor1(a2); a2 += dpp_xor2(a2); a2 += __shfl_xor(a2, 4);          \
        a3 += dpp_xor1(a3); a3 += dpp_xor2(a3); a3 += __shfl_xor(a3, 4);          \
        const float p = (kk & 1) ? ((kk & 2) ? a3 : a1) : ((kk & 2) ? a2 : a0);   \
        const float hn = fast_tanh(xc + p);                                       \
        if (act) {                                                                \
            encb[(size_t)t_ * HH + jw] = hn;                                      \
            *(_Float16*)(hwr + kk * 144 + g * 2) = (_Float16)hn;                  \
        }                                                                         \
        asm volatile("s_waitcnt lgkmcnt(0)\n\ts_barrier" ::: "memory");           \
        { const char* tmp_ = hrd; hrd = hwr; hwr = (char*)tmp_; }                 \
    }

    for (int tb = 0; tb < TT; tb += 4) {
        SCAN_STEP(tb,     0)
        SCAN_STEP(tb + 1, 1)
        SCAN_STEP(tb + 2, 2)
        SCAN_STEP(tb + 3, 3)
    }
#undef SCAN_STEP
}

// ---------------- K3: heads + tridiagonal fill ----------------
__global__ __launch_bounds__(256) void head_kernel(
    const float* __restrict__ enc,
    const float* __restrict__ W_mean, const float* __restrict__ b_mean,
    const float* __restrict__ W_bd, const float* __restrict__ b_bd,
    float* __restrict__ mean_out, float* __restrict__ prec)
{
    const int b = blockIdx.x >> 6;
    const int t0 = (blockIdx.x & 63) * 8;
    __shared__ __align__(16) float erow[9][HH];  // rows t0-1 .. t0+7
    __shared__ float vals[8][32];

    const int tid = threadIdx.x;
    {
        // row t0-1 (for t0==0,b==0 this reads the tail of xp — harmless, discarded)
        const float4* src = (const float4*)(enc + ((size_t)b * TT + t0) * HH - HH);
        float4* dst = (float4*)erow;
        for (int i = tid; i < 9 * (HH / 4); i += 256) dst[i] = src[i];
    }

    const int g = tid >> 3, m = tid & 7;
    const float* wrow;
    float bias;
    if (g < 8)       { wrow = W_mean + (size_t)g * HH;      bias = b_mean[g]; }
    else if (g < 24) { wrow = W_bd + (size_t)(g - 8) * HH;  bias = b_bd[g - 8]; }
    else             { wrow = W_bd + (size_t)(g - 16) * HH; bias = b_bd[g - 16]; }

    float4 wv[8];
#pragma unroll
    for (int i = 0; i < 8; ++i) wv[i] = ((const float4*)wrow)[m * 8 + i];

    __syncthreads();

    for (int r = 0; r < 8; ++r) {
        const float* src = (g >= 24) ? erow[r] : erow[r + 1];
        float acc = 0.f;
#pragma unroll
        for (int i = 0; i < 8; ++i) {
            const float4 hv = ((const float4*)src)[m * 8 + i];
            acc += wv[i].x * hv.x + wv[i].y * hv.y + wv[i].z * hv.z + wv[i].w * hv.w;
        }
        acc += __shfl_xor(acc, 1);
        acc += __shfl_xor(acc, 2);
        acc += __shfl_xor(acc, 4);
        if (m == 0) vals[r][g] = acc + bias;
    }
    __syncthreads();

    // write phase: 256 threads = 8 r-slots x 32 lanes
    const int r = tid >> 5, s = tid & 31;
    const int t = t0 + r;
    if (s < DD) {
        mean_out[((size_t)b * TT + t) * DD + s] = vals[r][s];
    } else if (s < 2 * DD) {
        const int d = s - DD;
        const float diag = vals[r][8 + d];
        const float off  = vals[r][16 + d];
        const float offp = (t > 0) ? vals[r][24 + d] : 0.f;
        const size_t rowbase = (((size_t)b * DD + d) * TT + t) * TT;
        prec[rowbase + t] = diag * diag + offp * offp + EPSF;
        if (t < TT - 1) {
            const float sv = diag * off;
            prec[rowbase + t + 1] = sv;                                 // (t, t+1)
            prec[(((size_t)b * DD + d) * TT + (t + 1)) * TT + t] = sv;  // (t+1, t)
        }
    }
}

extern "C" void kernel_launch(void* const* d_in, const int* in_sizes, int n_in,
                              void* d_out, int out_size, void* d_ws, size_t ws_size,
                              hipStream_t stream) {
    const float* y      = (const float*)d_in[0];
    const float* W_ih   = (const float*)d_in[1];
    const float* W_hh   = (const float*)d_in[2];
    const float* b_ih   = (const float*)d_in[3];
    const float* b_hh   = (const float*)d_in[4];
    const float* W_mean = (const float*)d_in[5];
    const float* b_mean = (const float*)d_in[6];
    const float* W_bd   = (const float*)d_in[7];
    const float* b_bd   = (const float*)d_in[8];

    float* out  = (float*)d_out;
    float* mean = out;                              // B*T*D floats
    float* prec = out + (size_t)BB * TT * DD;       // B*D*T*T floats

    float* xp  = (float*)d_ws;                      // B*T*H floats = 8 MB
    float* enc = xp + (size_t)BB * TT * HH;         // B*T*H floats = 8 MB

    xproj_kernel<<<512, 512, 0, stream>>>(y, W_ih, b_ih, b_hh, xp);
    scan_fill_kernel<<<1008, 512, 0, stream>>>(xp, W_hh, enc, prec);
    head_kernel<<<1024, 256, 0, stream>>>(enc, W_mean, b_mean, W_bd, b_bd, mean, prec);
}

// Round 7
// 406.573 us; speedup vs baseline: 2.9524x; 1.1302x over previous
//
#include <hip/hip_runtime.h>
#include <math.h>

#define BB 16
#define TT 512
#define IND 128
#define HH 256
#define DD 8
#define EPSF 1e-5f

typedef _Float16 h2_t __attribute__((ext_vector_type(2)));
typedef float f32x4 __attribute__((ext_vector_type(4)));

__device__ __forceinline__ float fast_tanh(float x) {
    // exp->inf gives 1, exp->0 gives -1; no clamp needed (verified r4-r6, same absmax)
    const float e = __expf(2.f * x);
    return 1.f - __fdividef(2.f, e + 1.f);
}

// quad_perm XOR swaps on the VALU pipe (no LDS traffic)
__device__ __forceinline__ float dpp_xor1(float x) {
    int i = __builtin_bit_cast(int, x);
    i = __builtin_amdgcn_update_dpp(i, i, 0xB1, 0xF, 0xF, true);  // {1,0,3,2}
    return __builtin_bit_cast(float, i);
}
__device__ __forceinline__ float dpp_xor2(float x) {
    int i = __builtin_bit_cast(int, x);
    i = __builtin_amdgcn_update_dpp(i, i, 0x4E, 0xF, 0xF, true);  // {2,3,0,1}
    return __builtin_bit_cast(float, i);
}

// ---------------- K1: x_proj[b,t,j] = y[b,t,:]·W_ih[j,:] + b_ih[j] + b_hh[j] ----------------
// All 16 rows staged in ONE coalesced burst (512 float4 = 1/thread) + ONE barrier,
// replacing the old 16x(single-wave stage + 2 barriers) serial chain. Reduce via DPP.
__global__ __launch_bounds__(512, 4) void xproj_kernel(
    const float* __restrict__ y, const float* __restrict__ W_ih,
    const float* __restrict__ b_ih, const float* __restrict__ b_hh,
    float* __restrict__ xp)
{
    __shared__ __align__(16) float ylds[16 * IND];  // 8 KB
    const int tid = threadIdx.x;
    const int j = tid >> 1;
    const int k4 = (tid & 1) * 4;

    float4 w[16];
    const float* wr = W_ih + (size_t)j * IND + k4;
#pragma unroll
    for (int i = 0; i < 16; ++i) w[i] = *(const float4*)(wr + i * 8);
#pragma unroll
    for (int i = 0; i < 16; ++i)
        asm volatile("" : "+v"(w[i].x), "+v"(w[i].y), "+v"(w[i].z), "+v"(w[i].w));
    const float bias = b_ih[j] + b_hh[j];

    const int row0 = blockIdx.x * 16;
    ((float4*)ylds)[tid] = ((const float4*)(y + (size_t)row0 * IND))[tid];
    __syncthreads();

#pragma unroll 4
    for (int r = 0; r < 16; ++r) {
        const float* yr = ylds + r * IND + k4;
        float a0 = 0.f, a1 = 0.f, a2 = 0.f, a3 = 0.f;
#pragma unroll
        for (int i = 0; i < 16; ++i) {
            const float4 hv = *(const float4*)(yr + i * 8);
            a0 = fmaf(hv.x, w[i].x, a0);
            a1 = fmaf(hv.y, w[i].y, a1);
            a2 = fmaf(hv.z, w[i].z, a2);
            a3 = fmaf(hv.w, w[i].w, a3);
        }
        float acc = (a0 + a1) + (a2 + a3);
        acc += dpp_xor1(acc);
        if ((tid & 1) == 0) xp[(size_t)(row0 + r) * HH + j] = acc + bias;
    }
}

// ---------------- K2: RNN scan (blocks 0..15) + prec zero-fill (blocks 16..) ----------------
// r1-proven structure: 256 threads (4 waves), lane = (j0 = tid>>2, k = tid&3) owns cols
// {j0+64m} with a 64-elem k-slice: 128 fdot2/lane, 64 weight VGPRs, 8 ds_read_b128/lane
// (144-B slice pitch, conflict-free), DPP quad reduce, all-lane b16 h-write, lgkm-only
// barrier. Trims vs r1: no-clamp tanh; xp-prefetch/enc-store via running pointers bumped
// once per 4-step group with literal offsets (S*1024B, fits 13-bit imm); last 4 steps
// peeled (no prefetch) so the per-step clamp/address chain is gone.
__global__ __launch_bounds__(256, 2) void scan_fill_kernel(
    const float* __restrict__ xp, const float* __restrict__ W_hh,
    float* __restrict__ enc, float* __restrict__ prec)
{
    if (blockIdx.x >= BB) {
        const size_t n4 = (size_t)BB * DD * TT * TT / 4;
        const f32x4 z = {0.f, 0.f, 0.f, 0.f};
        f32x4* p4 = (f32x4*)prec;
        size_t idx = (size_t)(blockIdx.x - BB) * blockDim.x + threadIdx.x;
        const size_t stride = (size_t)(gridDim.x - BB) * blockDim.x;
        for (; idx < n4; idx += stride) p4[idx] = z;
        return;
    }

    const int b   = blockIdx.x;
    const int tid = threadIdx.x;
    const int j0  = tid >> 2;      // 0..63
    const int k   = tid & 3;       // 64-elem slice AND owned-col selector
    const int jw  = j0 + 64 * k;   // col this lane finalizes

    // h layout: slice s at byte s*144, col j at (j>>6)*144 + (j&63)*2
    __shared__ __align__(16) char hbufA[4 * 144];
    __shared__ __align__(16) char hbufB[4 * 144];

    // weights: w[m][i] = (W_hh[j0+64m][64k+2i], W_hh[j0+64m][64k+2i+1]), i<32 (64 VGPR)
    h2_t w[4][32];
#pragma unroll
    for (int m = 0; m < 4; ++m) {
        const float* wr = W_hh + (size_t)(j0 + 64 * m) * HH + (size_t)k * 64;
#pragma unroll
        for (int i = 0; i < 32; ++i) {
            h2_t v;
            v.x = (_Float16)wr[2 * i];
            v.y = (_Float16)wr[2 * i + 1];
            w[m][i] = v;
        }
    }
#pragma unroll
    for (int m = 0; m < 4; ++m)
#pragma unroll
        for (int i = 0; i < 32; ++i) {
            int tmp = __builtin_bit_cast(int, w[m][i]);
            asm volatile("" : "+v"(tmp));
            w[m][i] = __builtin_bit_cast(h2_t, tmp);
        }

    // zero-init hbufA (pads don't matter: never read)
    if (tid < 128) {
        const int m = 2 * tid;
        h2_t z; z.x = (_Float16)0.f; z.y = (_Float16)0.f;
        *(h2_t*)(hbufA + (m >> 6) * 144 + (m & 63) * 2) = z;
    }

    const float* xpb  = xp  + (size_t)b * TT * HH;

    // 4-deep rotating xp prefetch; xpf points at the next prefetch group (t=4..7)
    float xbuf[4];
#pragma unroll
    for (int s = 0; s < 4; ++s) xbuf[s] = xpb[(size_t)s * HH + jw];
    const float* xpf = xpb + (size_t)4 * HH + jw;
    float*      encp = enc + (size_t)b * TT * HH + jw;

    const int roff = k * 144;            // LDS read base (slice k)
    const int hoff = k * 144 + j0 * 2;   // LDS write addr for col jw

    __syncthreads();

    const char* hrd = hbufA;
    char* hwr = hbufB;

#define SCAN_STEP(S, PF)                                                          \
    {                                                                             \
        const float xc = xbuf[S];                                                 \
        if (PF) xbuf[S] = xpf[(S) * HH];                                          \
        float a0 = 0.f, a1 = 0.f, a2 = 0.f, a3 = 0.f;                             \
        const float4* hp = (const float4*)(hrd + roff);                           \
        _Pragma("unroll")                                                         \
        for (int i = 0; i < 8; ++i) {                                             \
            union { float4 f4; h2_t h[4]; } u;                                    \
            u.f4 = hp[i];                                                         \
            _Pragma("unroll")                                                     \
            for (int q = 0; q < 4; ++q) {                                         \
                a0 = __builtin_amdgcn_fdot2(u.h[q], w[0][4 * i + q], a0, false);  \
                a1 = __builtin_amdgcn_fdot2(u.h[q], w[1][4 * i + q], a1, false);  \
                a2 = __builtin_amdgcn_fdot2(u.h[q], w[2][4 * i + q], a2, false);  \
                a3 = __builtin_amdgcn_fdot2(u.h[q], w[3][4 * i + q], a3, false);  \
            }                                                                     \
        }                                                                         \
        a0 += dpp_xor1(a0); a0 += dpp_xor2(a0);                                   \
        a1 += dpp_xor1(a1); a1 += dpp_xor2(a1);                                   \
        a2 += dpp_xor1(a2); a2 += dpp_xor2(a2);                                   \
        a3 += dpp_xor1(a3); a3 += dpp_xor2(a3);                                   \
        const float p = (k & 1) ? ((k & 2) ? a3 : a1) : ((k & 2) ? a2 : a0);      \
        const float hn = fast_tanh(xc + p);                                       \
        encp[(S) * HH] = hn;                                                      \
        *(_Float16*)(hwr + hoff) = (_Float16)hn;                                  \
        asm volatile("s_waitcnt lgkmcnt(0)\n\ts_barrier" ::: "memory");           \
        { const char* tmp_ = hrd; hrd = hwr; hwr = (char*)tmp_; }                 \
    }

    // groups tb=0..504: steps t=tb..tb+3, prefetch t=tb+4..tb+7 (<=511: in bounds)
    for (int tb = 0; tb < TT - 4; tb += 4) {
        SCAN_STEP(0, 1)
        SCAN_STEP(1, 1)
        SCAN_STEP(2, 1)
        SCAN_STEP(3, 1)
        xpf  += 4 * HH;
        encp += 4 * HH;
    }
    // tail t=508..511: already prefetched, no further loads
    SCAN_STEP(0, 0)
    SCAN_STEP(1, 0)
    SCAN_STEP(2, 0)
    SCAN_STEP(3, 0)
#undef SCAN_STEP
}

// ---------------- K3: heads + tridiagonal fill ----------------
__global__ __launch_bounds__(256) void head_kernel(
    const float* __restrict__ enc,
    const float* __restrict__ W_mean, const float* __restrict__ b_mean,
    const float* __restrict__ W_bd, const float* __restrict__ b_bd,
    float* __restrict__ mean_out, float* __restrict__ prec)
{
    const int b = blockIdx.x >> 6;
    const int t0 = (blockIdx.x & 63) * 8;
    __shared__ __align__(16) float erow[9][HH];  // rows t0-1 .. t0+7
    __shared__ float vals[8][32];

    const int tid = threadIdx.x;
    {
        // row t0-1 (for t0==0,b==0 this reads the tail of xp — harmless, discarded)
        const float4* src = (const float4*)(enc + ((size_t)b * TT + t0) * HH - HH);
        float4* dst = (float4*)erow;
        for (int i = tid; i < 9 * (HH / 4); i += 256) dst[i] = src[i];
    }

    const int g = tid >> 3, m = tid & 7;
    const float* wrow;
    float bias;
    if (g < 8)       { wrow = W_mean + (size_t)g * HH;      bias = b_mean[g]; }
    else if (g < 24) { wrow = W_bd + (size_t)(g - 8) * HH;  bias = b_bd[g - 8]; }
    else             { wrow = W_bd + (size_t)(g - 16) * HH; bias = b_bd[g - 16]; }

    float4 wv[8];
#pragma unroll
    for (int i = 0; i < 8; ++i) wv[i] = ((const float4*)wrow)[m * 8 + i];

    __syncthreads();

    for (int r = 0; r < 8; ++r) {
        const float* src = (g >= 24) ? erow[r] : erow[r + 1];
        float acc = 0.f;
#pragma unroll
        for (int i = 0; i < 8; ++i) {
            const float4 hv = ((const float4*)src)[m * 8 + i];
            acc += wv[i].x * hv.x + wv[i].y * hv.y + wv[i].z * hv.z + wv[i].w * hv.w;
        }
        acc += dpp_xor1(acc);
        acc += dpp_xor2(acc);
        acc += __shfl_xor(acc, 4);
        if (m == 0) vals[r][g] = acc + bias;
    }
    __syncthreads();

    // write phase: 256 threads = 8 r-slots x 32 lanes
    const int r = tid >> 5, s = tid & 31;
    const int t = t0 + r;
    if (s < DD) {
        mean_out[((size_t)b * TT + t) * DD + s] = vals[r][s];
    } else if (s < 2 * DD) {
        const int d = s - DD;
        const float diag = vals[r][8 + d];
        const float off  = vals[r][16 + d];
        const float offp = (t > 0) ? vals[r][24 + d] : 0.f;
        const size_t rowbase = (((size_t)b * DD + d) * TT + t) * TT;
        prec[rowbase + t] = diag * diag + offp * offp + EPSF;
        if (t < TT - 1) {
            const float sv = diag * off;
            prec[rowbase + t + 1] = sv;                                 // (t, t+1)
            prec[(((size_t)b * DD + d) * TT + (t + 1)) * TT + t] = sv;  // (t+1, t)
        }
    }
}

extern "C" void kernel_launch(void* const* d_in, const int* in_sizes, int n_in,
                              void* d_out, int out_size, void* d_ws, size_t ws_size,
                              hipStream_t stream) {
    const float* y      = (const float*)d_in[0];
    const float* W_ih   = (const float*)d_in[1];
    const float* W_hh   = (const float*)d_in[2];
    const float* b_ih   = (const float*)d_in[3];
    const float* b_hh   = (const float*)d_in[4];
    const float* W_mean = (const float*)d_in[5];
    const float* b_mean = (const float*)d_in[6];
    const float* W_bd   = (const float*)d_in[7];
    const float* b_bd   = (const float*)d_in[8];

    float* out  = (float*)d_out;
    float* mean = out;                              // B*T*D floats
    float* prec = out + (size_t)BB * TT * DD;       // B*D*T*T floats

    float* xp  = (float*)d_ws;                      // B*T*H floats = 8 MB
    float* enc = xp + (size_t)BB * TT * HH;         // B*T*H floats = 8 MB

    xproj_kernel<<<512, 512, 0, stream>>>(y, W_ih, b_ih, b_hh, xp);
    scan_fill_kernel<<<1008, 256, 0, stream>>>(xp, W_hh, enc, prec);
    head_kernel<<<1024, 256, 0, stream>>>(enc, W_mean, b_mean, W_bd, b_bd, mean, prec);
}